// Round 16
// baseline (92.194 us; speedup 1.0000x reference)
//
#include <hip/hip_runtime.h>
#include <hip/hip_fp16.h>
#include <math.h>

#define BB   4
#define C_   128
#define H_   96
#define W_   192
#define COUT 128
#define DG_  2
#define CG_  64
#define K_   9
#define HO   96
#define WO   192
#define HW   (H_ * W_)       // 18432
#define OMCH 54
#define RDIM (C_ * K_)       // 1152
#define NKS  (RDIM / 32)     // 36 K-steps
#define CSTEP 2              // K-steps per chunk (one gk per chunk)
#define NCH  (NKS / CSTEP)   // 18 chunks
#define VROW 18              // padded uints per val row (bank-walk stride)

typedef __attribute__((ext_vector_type(8))) _Float16 f16x8;
typedef __attribute__((ext_vector_type(4))) float f32x4;

static __device__ __forceinline__ ushort f2bf(float f) {
  union { float f; uint u; } v; v.f = f;
  uint r = v.u + 0x7fff + ((v.u >> 16) & 1);   // RNE
  return (ushort)(r >> 16);
}

// ---------------------------------------------------------------------------
// Prep: WtA  = main-GEMM A, fragment-major f16 (R12-proven layout, M=128);
//       Awo2 = offset-GEMM A, fragment-major f16 (M=64: rows g*32+j, j<27).
// ---------------------------------------------------------------------------
__global__ __launch_bounds__(256) void prep_k(
    const float* __restrict__ wd, const float* __restrict__ wo,
    ushort* __restrict__ WtA, ushort* __restrict__ Awo2) {
  int i = blockIdx.x * 256 + threadIdx.x;
  if (i < 128 * RDIM) {
    int blkA = i >> 9, within = i & 511;
    int oct = within >> 7, colA = (within >> 3) & 15, j = within & 7;
    int m = blkA & 1, wvq = (blkA >> 1) & 3, s = blkA >> 3;
    int o = wvq * 32 + m * 16 + colA;
    int r = s * 32 + oct * 8 + j;
    int g = r / 576, t = r - g * 576;
    int k = t >> 6, cg = t & 63;
    WtA[i] = __half_as_ushort(__float2half(wd[((size_t)o * C_ + g * 64 + cg) * 9 + k]));
  }
  if (i < 64 * RDIM) {
    int blkA = i >> 9, within = i & 511;
    int oct = within >> 7, colA = (within >> 3) & 15, j = within & 7;
    int wv2 = blkA & 3, s = blkA >> 2;
    int o2 = wv2 * 16 + colA;
    int r = s * 32 + oct * 8 + j;
    int g = r / 576, t = r - g * 576;
    int k = t >> 6, cg = t & 63;
    int g2 = o2 >> 5, j2 = o2 & 31;
    float v = ((g2 == g) && (j2 < 27))
                ? wo[(((size_t)(g2 * 27 + j2)) * 64 + cg) * 9 + k] : 0.f;
    Awo2[i] = __half_as_ushort(__float2half(v));
  }
}

// ---------------------------------------------------------------------------
// NCHW -> NHWC fp16 transpose of x (R11-proven).
// ---------------------------------------------------------------------------
__global__ __launch_bounds__(256) void xt_k(
    const float* __restrict__ x, __half* __restrict__ xT) {
  __shared__ float t[128][65];
  int blk = blockIdx.x;
  int b = blk / 288, p0 = (blk % 288) * 64;
  int q = threadIdx.x >> 6, l = threadIdx.x & 63;
  const float* xb = x + (size_t)b * C_ * HW;
#pragma unroll
  for (int it = 0; it < 32; ++it) {
    int c = q * 32 + it;
    t[c][l] = xb[(size_t)c * HW + p0 + l];
  }
  __syncthreads();
  uint* xTb = (uint*)(xT + (size_t)b * HW * 128);
#pragma unroll
  for (int it = 0; it < 16; ++it) {
    int px = q * 16 + it;
    union { __half2 h; uint u; } pk;
    pk.h = __half2{__float2half(t[2 * l][px]), __float2half(t[2 * l + 1][px])};
    xTb[(size_t)(p0 + px) * 64 + l] = pk.u;
  }
}

// ---------------------------------------------------------------------------
// Offset conv (R15 pipeline, CSTEP=2): 64 px x 64 rows, NHWC f16,
// fixed-displacement B loads, zero-pad mask, 18 chunks, dbuf VROW-18 LDS.
// ---------------------------------------------------------------------------
__global__ __launch_bounds__(256, 6) void offset_nhwc_k(
    const __half* __restrict__ xT, const ushort* __restrict__ Awo2,
    const float* __restrict__ b_offset, float* __restrict__ om) {
  __shared__ uint s_val[2][CSTEP * 64 * VROW];   // 2 x 9216 B

  int bid = blockIdx.x;
  int blk = (bid & 7) * 144 + (bid >> 3);    // bijective, 1152 % 8 == 0
  int wt = blk % 3, bh = blk / 3;
  int ho = bh % HO, b = bh / HO;
  int wo0 = wt * 64;
  int tid = threadIdx.x;
  int lane = tid & 63, wv = tid >> 6;
  int sub = lane >> 3, q = lane & 7;
  int col = lane & 15, oct = lane >> 4;

  const __half* xTb = xT + (size_t)b * HW * 128;

  f32x4 acc[4];
#pragma unroll
  for (int n = 0; n < 4; ++n) acc[n] = (f32x4){0.f, 0.f, 0.f, 0.f};

  uint4 C0[2];
  uint  MK[2];
  int   IX[2];

  auto issue_chunk = [&](int c) {
#pragma unroll
    for (int t = 0; t < 2; ++t) {
      int po = wv * 2 + t;               // 0..7
      int gk = c;
      int px = po * 8 + sub;
      int g = gk >= 9, k = gk - 9 * g;
      int dy = k / 3, dx = k - dy * 3;
      int y  = ho - 2 + 2 * dy;
      int xc = wo0 + px - 2 + 2 * dx;
      bool ok = (y >= 0) & (y < H_) & (xc >= 0) & (xc < W_);
      int yc  = min(max(y, 0), H_ - 1);
      int xcc = min(max(xc, 0), W_ - 1);
      const __half* p = xTb + (size_t)(yc * W_ + xcc) * 128 + g * 64 + q * 8;
      C0[t] = *(const uint4*)(p);
      MK[t] = ok ? 0x3c003c00u : 0u;     // half2(1,1) or half2(0,0)
      int step_local = q >> 2;
      IX[t] = (step_local * 64 + px) * VROW + (q & 3) * 4;
    }
  };

  auto finish_chunk = [&](int nb) {
#pragma unroll
    for (int t = 0; t < 2; ++t) {
      union { __half2 h2; uint u; } m; m.u = MK[t];
      uint res[4];
      const uint* a = (const uint*)&C0[t];
#pragma unroll
      for (int h = 0; h < 4; ++h) {
        union { __half2 h2; uint u; } p, vv;
        p.u = a[h];
        vv.h2 = __hmul2(p.h2, m.h2);
        res[h] = vv.u;
      }
      *(uint4*)&s_val[nb][IX[t]] = make_uint4(res[0], res[1], res[2], res[3]);
    }
  };

  auto mfma_chunk = [&](int c, int cb) {
#pragma unroll
    for (int ls = 0; ls < CSTEP; ++ls) {
      int s = c * CSTEP + ls;
      const ushort* ab = Awo2 + (size_t)(s * 4 + wv) * 512 + (oct * 16 + col) * 8;
      f16x8 a0 = *(const f16x8*)(ab);
#pragma unroll
      for (int n = 0; n < 4; ++n) {
        f16x8 bfr = *(const f16x8*)
            &s_val[cb][(ls * 64 + n * 16 + col) * VROW + oct * 4];
        acc[n] = __builtin_amdgcn_mfma_f32_16x16x32_f16(a0, bfr, acc[n], 0, 0, 0);
      }
    }
  };

  issue_chunk(0);
  finish_chunk(0);
  __syncthreads();

  for (int c = 0; c < NCH; ++c) {
    if (c < NCH - 1) issue_chunk(c + 1);
    mfma_chunk(c, c & 1);
    if (c < NCH - 1) finish_chunk((c + 1) & 1);
    __syncthreads();
  }

  // epilogue: rows o2 = wv*16 + oct*4 + ri; g=o2>>5, j=o2&31, j<27 real
#pragma unroll
  for (int n = 0; n < 4; ++n)
#pragma unroll
    for (int ri = 0; ri < 4; ++ri) {
      int o2 = wv * 16 + oct * 4 + ri;
      int g = o2 >> 5, j = o2 & 31;
      if (j < 27) {
        int ch = g * 27 + j;
        om[((size_t)(b * OMCH + ch) * HO + ho) * WO + wo0 + n * 16 + col] =
            acc[n][ri] + b_offset[ch];
      }
    }
}

// ---------------------------------------------------------------------------
// Main kernel (R14 math, CSTEP=2): 64 px x 128 Cout, 18 chunks, VROW-18 pad,
// packed __hfma2 combine, mfma_f32_16x16x32_f16. LDS 32.3 KB -> 4 blocks/CU.
// ---------------------------------------------------------------------------
__global__ __launch_bounds__(256, 4) void deform_main_k(
    const __half* __restrict__ xT, const float* __restrict__ om,
    const ushort* __restrict__ WtA, float* __restrict__ out) {
  __shared__ uint  s_addr[18 * 64];               // 4608 B
  __shared__ uint2 s_wq[18 * 64];                 // 9216 B
  __shared__ uint  s_val[2][CSTEP * 64 * VROW];   // 2 x 9216 B

  int bid = blockIdx.x;
  int blk = (bid & 7) * 144 + (bid >> 3);    // bijective, 1152 % 8 == 0
  int wt = blk % 3, bh = blk / 3;
  int ho = bh % HO, b = bh / HO;
  int wo0 = wt * 64;
  int tid = threadIdx.x;
  int lane = tid & 63, wv = tid >> 6;

  // ---- phase 0: canonical in-bounds bilinear coefficients (proven math) ----
  for (int e = tid; e < 18 * 64; e += 256) {
    int px = e & 63, gk = e >> 6;
    int g = gk / 9, k = gk - g * 9;
    int wo = wo0 + px;
    const float* omb = om + (size_t)b * OMCH * HW + (size_t)ho * WO + wo;
    float offy = omb[(size_t)(g * 18 + k * 2 + 0) * HW];
    float offx = omb[(size_t)(g * 18 + k * 2 + 1) * HW];
    float z    = omb[(size_t)(36 + g * 9 + k) * HW];
    float msk  = 2.f / (1.f + __expf(-z));
    float py = (float)(ho - 2 + (k / 3) * 2) + offy;
    float px_ = (float)(wo - 2 + (k % 3) * 2) + offx;
    float y0f = floorf(py), x0f = floorf(px_);
    int   y0 = (int)y0f, x0 = (int)x0f;
    float ty = py - y0f, tx = px_ - x0f;
    float wy0 = (y0 >= 0 && y0 < H_)      ? (1.f - ty) : 0.f;
    float wy1 = (y0 >= -1 && y0 < H_ - 1) ? ty         : 0.f;
    float wx0 = (x0 >= 0 && x0 < W_)      ? (1.f - tx) : 0.f;
    float wx1 = (x0 >= -1 && x0 < W_ - 1) ? tx         : 0.f;
    int yb  = min(max(y0, 0), H_ - 2);
    int xb_ = min(max(x0, 0), W_ - 2);
    float wAy = (y0 == yb      ? wy0 : 0.f) + (y0 + 1 == yb      ? wy1 : 0.f);
    float wBy = (y0 == yb + 1  ? wy0 : 0.f) + (y0 + 1 == yb + 1  ? wy1 : 0.f);
    float wAx = (x0 == xb_     ? wx0 : 0.f) + (x0 + 1 == xb_     ? wx1 : 0.f);
    float wBx = (x0 == xb_ + 1 ? wx0 : 0.f) + (x0 + 1 == xb_ + 1 ? wx1 : 0.f);
    s_addr[e] = (uint)((yb * W_ + xb_) * 128);
    union { __half2 h; uint u; } uA, uB;
    uA.h = __half2{__float2half(wAy * wAx * msk), __float2half(wAy * wBx * msk)};
    uB.h = __half2{__float2half(wBy * wAx * msk), __float2half(wBy * wBx * msk)};
    s_wq[e] = make_uint2(uA.u, uB.u);
  }

  const __half* xTb = xT + (size_t)b * HW * 128;
  int sub = lane >> 3, q = lane & 7;     // px-sub(8), ch-oct(8)
  int col = lane & 15, oct = lane >> 4;  // GEMM lane roles

  f32x4 acc[2][4];
#pragma unroll
  for (int m = 0; m < 2; ++m)
#pragma unroll
    for (int n = 0; n < 4; ++n) acc[m][n] = (f32x4){0.f, 0.f, 0.f, 0.f};

  uint4 C0[2], C1[2], C2[2], C3[2];
  uint2 WQ[2];
  int   IX[2];

  auto issue_chunk = [&](int c) {
#pragma unroll
    for (int t = 0; t < 2; ++t) {
      int po = wv * 2 + t;               // 0..7
      int gk = c;
      int px = po * 8 + sub;
      int ci = gk * 64 + px;
      uint base = s_addr[ci];
      WQ[t] = s_wq[ci];
      int g = gk >= 9;
      const __half* p = xTb + base + g * 64 + q * 8;
      C0[t] = *(const uint4*)(p);
      C1[t] = *(const uint4*)(p + 128);
      C2[t] = *(const uint4*)(p + W_ * 128);
      C3[t] = *(const uint4*)(p + W_ * 128 + 128);
      int step_local = q >> 2;
      int row = step_local * 64 + px;
      IX[t] = row * VROW + (q & 3) * 4;
    }
  };

  auto finish_chunk = [&](int nb) {
#pragma unroll
    for (int t = 0; t < 2; ++t) {
      union { __half2 h; uint u; } w0, w1;
      w0.u = WQ[t].x; w1.u = WQ[t].y;
      __half2 wAx = __low2half2(w0.h), wAy = __high2half2(w0.h);
      __half2 wBx = __low2half2(w1.h), wBy = __high2half2(w1.h);
      uint res[4];
      const uint* a  = (const uint*)&C0[t];
      const uint* b1 = (const uint*)&C1[t];
      const uint* c2 = (const uint*)&C2[t];
      const uint* d  = (const uint*)&C3[t];
#pragma unroll
      for (int h = 0; h < 4; ++h) {
        union { __half2 h2; uint u; } p0, p1, p2, p3, vv;
        p0.u = a[h]; p1.u = b1[h]; p2.u = c2[h]; p3.u = d[h];
        __half2 v = __hmul2(p0.h2, wAx);
        v = __hfma2(p1.h2, wAy, v);
        v = __hfma2(p2.h2, wBx, v);
        v = __hfma2(p3.h2, wBy, v);
        vv.h2 = v;
        res[h] = vv.u;
      }
      *(uint4*)&s_val[nb][IX[t]] = make_uint4(res[0], res[1], res[2], res[3]);
    }
  };

  auto mfma_chunk = [&](int c, int cb) {
#pragma unroll
    for (int ls = 0; ls < CSTEP; ++ls) {
      int s = c * CSTEP + ls;
      const ushort* ab = WtA + (size_t)((s * 4 + wv) * 2) * 512 + (oct * 16 + col) * 8;
      f16x8 a0 = *(const f16x8*)(ab);
      f16x8 a1 = *(const f16x8*)(ab + 512);
#pragma unroll
      for (int n = 0; n < 4; ++n) {
        f16x8 bfr = *(const f16x8*)
            &s_val[cb][(ls * 64 + n * 16 + col) * VROW + oct * 4];
        acc[0][n] = __builtin_amdgcn_mfma_f32_16x16x32_f16(a0, bfr, acc[0][n], 0, 0, 0);
        acc[1][n] = __builtin_amdgcn_mfma_f32_16x16x32_f16(a1, bfr, acc[1][n], 0, 0, 0);
      }
    }
  };

  __syncthreads();                  // coeffs ready
  issue_chunk(0);
  finish_chunk(0);
  __syncthreads();                  // buf0 ready

  for (int c = 0; c < NCH; ++c) {
    if (c < NCH - 1) issue_chunk(c + 1);
    mfma_chunk(c, c & 1);
    if (c < NCH - 1) finish_chunk((c + 1) & 1);
    __syncthreads();
  }

  // ---- epilogue ----
#pragma unroll
  for (int m = 0; m < 2; ++m)
#pragma unroll
    for (int n = 0; n < 4; ++n)
#pragma unroll
      for (int ri = 0; ri < 4; ++ri) {
        int o = wv * 32 + m * 16 + oct * 4 + ri;
        out[((size_t)(b * COUT + o) * HO + ho) * WO + wo0 + n * 16 + col] = acc[m][n][ri];
      }
}

// ---------------------------------------------------------------------------
extern "C" void kernel_launch(void* const* d_in, const int* in_sizes, int n_in,
                              void* d_out, int out_size, void* d_ws, size_t ws_size,
                              hipStream_t stream) {
  const float* x        = (const float*)d_in[0];
  const float* w_offset = (const float*)d_in[1];
  const float* b_offset = (const float*)d_in[2];
  const float* w_deform = (const float*)d_in[3];
  float* out = (float*)d_out;

  char* ws = (char*)d_ws;
  float*  om   = (float*)ws;                             // 15,925,248 B
  ushort* WtA  = (ushort*)(ws + 15925248);               //    294,912 B
  ushort* Awo2 = (ushort*)(ws + 15925248 + 294912);      //    147,456 B
  __half* xT   = (__half*)(ws + 15925248 + 294912 + 147456);  // 18,874,368 B

  prep_k<<<576, 256, 0, stream>>>(w_deform, w_offset, WtA, Awo2);
  xt_k<<<1152, 256, 0, stream>>>(x, xT);
  offset_nhwc_k<<<1152, 256, 0, stream>>>(xT, Awo2, b_offset, om);
  deform_main_k<<<1152, 256, 0, stream>>>(xT, om, WtA, out);
}